// Round 5
// baseline (209.875 us; speedup 1.0000x reference)
//
#include <hip/hip_runtime.h>
#include <hip/hip_bf16.h>

#define BATCH 8192
#define KDIM  2048   // NUM_INPUTS*UNITS
#define NDIM  2048   // NUM_OUTPUTS*UNITS

typedef short bf16x8 __attribute__((ext_vector_type(8)));
typedef float f32x4  __attribute__((ext_vector_type(4)));

__device__ __forceinline__ unsigned short f2bf(float f) {
    unsigned int u = __float_as_uint(f);
    u = u + 0x7fffu + ((u >> 16) & 1u);   // round-to-nearest-even
    return (unsigned short)(u >> 16);
}

// ---------- pack A: x fp32 [8192][2048] -> bf16 (coalesced float4 -> bf16x8) ----------
__global__ __launch_bounds__(256) void pack_a(const float* __restrict__ x,
                                              short* __restrict__ a) {
    int h = blockIdx.x * 256 + threadIdx.x;
    const f32x4* xv = (const f32x4*)x;
    f32x4 v0 = xv[(size_t)h * 2];
    f32x4 v1 = xv[(size_t)h * 2 + 1];
    bf16x8 r;
    r[0] = (short)f2bf(v0[0]); r[1] = (short)f2bf(v0[1]);
    r[2] = (short)f2bf(v0[2]); r[3] = (short)f2bf(v0[3]);
    r[4] = (short)f2bf(v1[0]); r[5] = (short)f2bf(v1[1]);
    r[6] = (short)f2bf(v1[2]); r[7] = (short)f2bf(v1[3]);
    ((bf16x8*)a)[h] = r;
}

// ---------- pack B via LDS transpose: Bp[j][k] = bf16(z[o,n]*T[o,n,u,v]) ----------
__global__ __launch_bounds__(256) void pack_b(const float* __restrict__ T,
                                              const float* __restrict__ u_param,
                                              const float* __restrict__ alpha,
                                              short* __restrict__ bp) {
    __shared__ short tl[256 * 33];   // [u][v'] with +1 pad, 16.5 KiB
    int bid = blockIdx.x;            // 512 blocks: o(8) x n(8) x vchunk(8)
    int o  = bid >> 6;
    int n  = (bid >> 3) & 7;
    int v0 = (bid & 7) * 32;
    int tid = threadIdx.x;

    float up = u_param[o * 8 + n];
    float t  = logf(up) - logf(1.0f - up) + logf(alpha[0]) * (1.0f / 0.9f);
    float s  = 1.0f / (1.0f + expf(-t));
    float z  = fminf(fmaxf(s * 1.2f - 0.1f, 0.0f), 1.0f);

    const f32x4* T4 = (const f32x4*)(T + ((size_t)(o * 8 + n) << 16));
#pragma unroll
    for (int it = 0; it < 8; ++it) {
        int f = it * 256 + tid;          // float4 task
        int u = f >> 3, vv = (f & 7) * 4;
        f32x4 val = T4[(u * 256 + v0 + vv) >> 2];
#pragma unroll
        for (int j = 0; j < 4; ++j)
            tl[u * 33 + vv + j] = (short)f2bf(z * val[j]);
    }
    __syncthreads();
#pragma unroll
    for (int it = 0; it < 4; ++it) {
        int g = it * 256 + tid;
        int v = g >> 5, ch = g & 31;
        bf16x8 r;
#pragma unroll
        for (int q = 0; q < 8; ++q) r[q] = tl[(ch * 8 + q) * 33 + v];
        *(bf16x8*)&bp[(size_t)(o * 256 + v0 + v) * KDIM + n * 256 + ch * 8] = r;
    }
}

// ---------- GEMM: 256x256, BK=64, 8 waves, 8-phase, REGISTER-PIPELINED frags ----------
// Phase p issues ds_reads for phase p+1's A-quadrant (afrX/afrY alternate) and runs
// MFMA on frags read last phase -> LDS drain overlaps MFMA. 1 barrier/phase.
// LDS swizzle: element_addr ^= (row&7)<<3 (0-conflict, verified R4). Same involution
// pre-applied to the global_load_lds SOURCE (linear LDS dest, rule 21).
#define SCB() __builtin_amdgcn_sched_barrier(0)
#define BAR1() do { SCB(); __builtin_amdgcn_s_barrier(); SCB(); } while (0)
#define WAITK(n) do { SCB(); asm volatile("s_waitcnt lgkmcnt(" #n ")" ::: "memory"); SCB(); } while (0)
#define WAITV4() do { SCB(); asm volatile("s_waitcnt vmcnt(4)" ::: "memory"); SCB(); } while (0)

#define LDB(buf) do { \
    int base = 32768 + (buf) * 16384 + (wc * 64 + l15) * 64 + hi8; \
    _Pragma("unroll") for (int nn = 0; nn < 4; ++nn) \
    _Pragma("unroll") for (int k8 = 0; k8 < 2; ++k8) \
        bfr[nn][k8] = *(const bf16x8*)&lds[(base + nn * 1024 + k8 * 32) ^ sx]; \
} while (0)

#define LDA(buf, q, SET) do { \
    int base = (buf) * 16384 + (wr * 128 + (q) * 32 + l15) * 64 + hi8; \
    _Pragma("unroll") for (int mm = 0; mm < 2; ++mm) \
    _Pragma("unroll") for (int k8 = 0; k8 < 2; ++k8) \
        SET[mm][k8] = *(const bf16x8*)&lds[(base + mm * 1024 + k8 * 32) ^ sx]; \
} while (0)

#define MM(q, SET) do { \
    __builtin_amdgcn_s_setprio(1); \
    _Pragma("unroll") for (int mm = 0; mm < 2; ++mm) \
    _Pragma("unroll") for (int nn = 0; nn < 4; ++nn) \
    _Pragma("unroll") for (int k8 = 0; k8 < 2; ++k8) \
        acc[(q)*2 + mm][nn] = __builtin_amdgcn_mfma_f32_16x16x32_bf16( \
            SET[mm][k8], bfr[nn][k8], acc[(q)*2 + mm][nn], 0, 0, 0); \
    __builtin_amdgcn_s_setprio(0); \
} while (0)

__global__ __launch_bounds__(512, 2) void gemm(const short* __restrict__ A,
                                               const short* __restrict__ B,
                                               float* __restrict__ C) {
    // LDS: A buf0 @0, A buf1 @16384, B buf0 @32768, B buf1 @49152 (elements). 128 KiB.
    __shared__ __align__(16) short lds[65536];

    const int tid  = threadIdx.x;
    const int lane = tid & 63;
    const int wid  = tid >> 6;
    const int wr = wid >> 2, wc = wid & 3;      // 2M x 4N waves; 128x64 out each
    const int l15 = lane & 15, hi8 = (lane >> 4) * 8;
    const int sx  = (lane & 7) << 3;            // read-side XOR: (row&7)<<3 elements

    int bid = blockIdx.x;
    int wg  = (bid & 7) * 32 + (bid >> 3);      // bijective XCD swizzle (256 wgs)
    int by = wg >> 3, bx = wg & 7;
    const int bm = by * 256, bn = bx * 256;

    // staging source coords: linear LDS dest L -> swizzled global (r,c); involution
    int r_[2], c_[2];
#pragma unroll
    for (int i = 0; i < 2; ++i) {
        int L = i * 4096 + tid * 8;                 // element index within half-tile
        int S = L ^ (((L >> 6) & 7) << 3);          // XOR col bits 3-5 with row bits 0-2
        r_[i] = S >> 6; c_[i] = S & 63;
    }

    auto stA = [&](int buf, int h, int kt) {
#pragma unroll
        for (int i = 0; i < 2; ++i) {
            const short* src = A + (size_t)(bm + h * 128 + r_[i]) * KDIM + kt * 64 + c_[i];
            __builtin_amdgcn_global_load_lds(
                (const __attribute__((address_space(1))) void*)src,
                (__attribute__((address_space(3))) void*)&lds[buf * 16384 + h * 8192 + i * 4096 + tid * 8],
                16, 0, 0);
        }
    };
    auto stB = [&](int buf, int h, int kt) {
#pragma unroll
        for (int i = 0; i < 2; ++i) {
            const short* src = B + (size_t)(bn + h * 128 + r_[i]) * KDIM + kt * 64 + c_[i];
            __builtin_amdgcn_global_load_lds(
                (const __attribute__((address_space(1))) void*)src,
                (__attribute__((address_space(3))) void*)&lds[32768 + buf * 16384 + h * 8192 + i * 4096 + tid * 8],
                16, 0, 0);
        }
    };

    f32x4  acc[8][4] = {};
    bf16x8 bfr[4][2];
    bf16x8 afrX[2][2], afrY[2][2];

    // ---- prologue: A(0),B(0) -> buf0; B(1) -> buf1; wait all but B(1) ----
    stA(0, 0, 0); stA(0, 1, 0);
    stB(0, 0, 0); stB(0, 1, 0);
    stB(1, 0, 1); stB(1, 1, 1);
    WAITV4();
    BAR1();

    // Stage schedule: P1,P2: A(t1)->Abuf1  P3,P4: B(t2)->Bbuf0
    //                 P5,P6: A(t2)->Abuf0  P7,P8: B(t3)->Bbuf1
    // vmcnt(4) at P4/P8 (2 newest half-tiles stay in flight across barriers).
    for (int i = 0; i < 16; ++i) {
        int t1 = 2 * i + 1, t2 = (2 * i + 2) & 31, t3 = (2 * i + 3) & 31;
        // P1: serial frag load (buf0 fresh), prefetch q1
        LDB(0); LDA(0, 0, afrX); stA(1, 0, t1);
        SCB();                       // keep q1 reads strictly after B+q0 (lgkm count)
        LDA(0, 1, afrY);
        WAITK(4); MM(0, afrX); BAR1();
        // P2
        LDA(0, 2, afrX); stA(1, 1, t1);
        WAITK(4); MM(1, afrY); BAR1();
        // P3
        LDA(0, 3, afrY); stB(0, 0, t2);
        WAITK(4); MM(2, afrX); BAR1();
        // P4
        stB(0, 1, t2);
        WAITK(0); MM(3, afrY);
        WAITV4(); BAR1();
        // P5: serial frag load (buf1 fresh), prefetch q1
        LDB(1); LDA(1, 0, afrX); stA(0, 0, t2);
        SCB();
        LDA(1, 1, afrY);
        WAITK(4); MM(0, afrX); BAR1();
        // P6
        LDA(1, 2, afrX); stA(0, 1, t2);
        WAITK(4); MM(1, afrY); BAR1();
        // P7
        LDA(1, 3, afrY); stB(1, 0, t3);
        WAITK(4); MM(2, afrX); BAR1();
        // P8
        stB(1, 1, t3);
        WAITK(0); MM(3, afrY);
        WAITV4(); BAR1();
    }
    asm volatile("s_waitcnt vmcnt(0)" ::: "memory");

    // epilogue: C/D layout col=lane&15, row=(lane>>4)*4+reg  [m89-verified]
    int r0 = bm + wr * 128 + (lane >> 4) * 4;
    int c0 = bn + wc * 64 + l15;
#pragma unroll
    for (int m = 0; m < 8; ++m)
#pragma unroll
        for (int nn = 0; nn < 4; ++nn)
#pragma unroll
            for (int r = 0; r < 4; ++r)
                C[(size_t)(r0 + m * 16 + r) * NDIM + c0 + nn * 16] = acc[m][nn][r];
}

extern "C" void kernel_launch(void* const* d_in, const int* in_sizes, int n_in,
                              void* d_out, int out_size, void* d_ws, size_t ws_size,
                              hipStream_t stream) {
    const float* x       = (const float*)d_in[0];   // [8192,8,256]
    const float* alpha   = (const float*)d_in[1];   // [1]
    const float* u_param = (const float*)d_in[2];   // [8,8]
    const float* T       = (const float*)d_in[3];   // [8,8,256,256]
    float* out = (float*)d_out;                     // [8192,8,256]

    short* Abf = (short*)d_ws;                                     // 32 MiB
    short* Bp  = (short*)((char*)d_ws + (size_t)BATCH * KDIM * 2); // 8 MiB

    hipLaunchKernelGGL(pack_a, dim3((BATCH * KDIM / 8) / 256), dim3(256), 0, stream, x, Abf);
    hipLaunchKernelGGL(pack_b, dim3(512), dim3(256), 0, stream, T, u_param, alpha, Bp);
    hipLaunchKernelGGL(gemm, dim3((BATCH / 256) * (NDIM / 256)), dim3(512), 0, stream,
                       Abf, Bp, out);
}

// Round 6
// 191.161 us; speedup vs baseline: 1.0979x; 1.0979x over previous
//
#include <hip/hip_runtime.h>
#include <hip/hip_bf16.h>

#define BATCH 8192
#define KDIM  2048   // NUM_INPUTS*UNITS
#define NDIM  2048   // NUM_OUTPUTS*UNITS

typedef short bf16x8  __attribute__((ext_vector_type(8)));
typedef float f32x4   __attribute__((ext_vector_type(4)));
typedef float f32x16  __attribute__((ext_vector_type(16)));

__device__ __forceinline__ unsigned short f2bf(float f) {
    unsigned int u = __float_as_uint(f);
    u = u + 0x7fffu + ((u >> 16) & 1u);   // round-to-nearest-even
    return (unsigned short)(u >> 16);
}

// ---------- pack A: x fp32 [8192][2048] -> bf16 (coalesced float4 -> bf16x8) ----------
__global__ __launch_bounds__(256) void pack_a(const float* __restrict__ x,
                                              short* __restrict__ a) {
    int h = blockIdx.x * 256 + threadIdx.x;
    const f32x4* xv = (const f32x4*)x;
    f32x4 v0 = xv[(size_t)h * 2];
    f32x4 v1 = xv[(size_t)h * 2 + 1];
    bf16x8 r;
    r[0] = (short)f2bf(v0[0]); r[1] = (short)f2bf(v0[1]);
    r[2] = (short)f2bf(v0[2]); r[3] = (short)f2bf(v0[3]);
    r[4] = (short)f2bf(v1[0]); r[5] = (short)f2bf(v1[1]);
    r[6] = (short)f2bf(v1[2]); r[7] = (short)f2bf(v1[3]);
    ((bf16x8*)a)[h] = r;
}

// ---------- pack B via LDS transpose: Bp[j][k] = bf16(z[o,n]*T[o,n,u,v]) ----------
__global__ __launch_bounds__(256) void pack_b(const float* __restrict__ T,
                                              const float* __restrict__ u_param,
                                              const float* __restrict__ alpha,
                                              short* __restrict__ bp) {
    __shared__ short tl[256 * 33];   // [u][v'] with +1 pad, 16.5 KiB
    int bid = blockIdx.x;            // 512 blocks: o(8) x n(8) x vchunk(8)
    int o  = bid >> 6;
    int n  = (bid >> 3) & 7;
    int v0 = (bid & 7) * 32;
    int tid = threadIdx.x;

    float up = u_param[o * 8 + n];
    float t  = logf(up) - logf(1.0f - up) + logf(alpha[0]) * (1.0f / 0.9f);
    float s  = 1.0f / (1.0f + expf(-t));
    float z  = fminf(fmaxf(s * 1.2f - 0.1f, 0.0f), 1.0f);

    const f32x4* T4 = (const f32x4*)(T + ((size_t)(o * 8 + n) << 16));
#pragma unroll
    for (int it = 0; it < 8; ++it) {
        int f = it * 256 + tid;          // float4 task
        int u = f >> 3, vv = (f & 7) * 4;
        f32x4 val = T4[(u * 256 + v0 + vv) >> 2];
#pragma unroll
        for (int j = 0; j < 4; ++j)
            tl[u * 33 + vv + j] = (short)f2bf(z * val[j]);
    }
    __syncthreads();
#pragma unroll
    for (int it = 0; it < 4; ++it) {
        int g = it * 256 + tid;
        int v = g >> 5, ch = g & 31;
        bf16x8 r;
#pragma unroll
        for (int q = 0; q < 8; ++q) r[q] = tl[(ch * 8 + q) * 33 + v];
        *(bf16x8*)&bp[(size_t)(o * 256 + v0 + v) * KDIM + n * 256 + ch * 8] = r;
    }
}

// ---------- GEMM: 256x256, BK=64, 8 waves, 8-phase (R4 schedule), 32x32x16 MFMA ----------
// Schedule identical to the verified R4 kernel (65us): per phase {ds_read frags,
// stage 1 half-tile, barrier, MFMA (compiler-placed lgkm waits), barrier};
// vmcnt(4) at P4/P8 only. LDS swizzle element^=(row&7)<<3 (0-conflict, R4-verified),
// same involution pre-applied to global_load_lds SOURCE (linear dest, rule 21).
// Shape swap 16x16x32 -> 32x32x16: +15-20% MFMA rate (m119), same LDS bytes.
#define SBAR() do { __builtin_amdgcn_sched_barrier(0); \
                    __builtin_amdgcn_s_barrier(); \
                    __builtin_amdgcn_sched_barrier(0); } while (0)

// A-frags for m-tile mt (4 k-steps), B-frags for 2 n-tiles x 4 k-steps.
#define LDA32(buf, mt) do { \
    int base = (buf) * 16384 + (wr * 128 + (mt) * 32 + l31) * 64 + hi8e; \
    _Pragma("unroll") for (int kk = 0; kk < 4; ++kk) \
        afr[kk] = *(const bf16x8*)&lds[(base + kk * 16) ^ sx]; \
} while (0)

#define LDB32(buf) do { \
    int base = 32768 + (buf) * 16384 + (wc * 64 + l31) * 64 + hi8e; \
    _Pragma("unroll") for (int nt = 0; nt < 2; ++nt) \
    _Pragma("unroll") for (int kk = 0; kk < 4; ++kk) \
        bfr[nt][kk] = *(const bf16x8*)&lds[(base + nt * 2048 + kk * 16) ^ sx]; \
} while (0)

// 8 MFMA of 32x32x16 per phase; nt-inner alternation gives 2 independent chains.
#define MM32(mt) do { \
    __builtin_amdgcn_s_setprio(1); \
    _Pragma("unroll") for (int kk = 0; kk < 4; ++kk) \
    _Pragma("unroll") for (int nt = 0; nt < 2; ++nt) \
        acc[mt][nt] = __builtin_amdgcn_mfma_f32_32x32x16_bf16( \
            afr[kk], bfr[nt][kk], acc[mt][nt], 0, 0, 0); \
    __builtin_amdgcn_s_setprio(0); \
} while (0)

__global__ __launch_bounds__(512, 2) void gemm(const short* __restrict__ A,
                                               const short* __restrict__ B,
                                               float* __restrict__ C) {
    // LDS: A buf0 @0, A buf1 @16384, B buf0 @32768, B buf1 @49152 (elements). 128 KiB.
    __shared__ __align__(16) short lds[65536];

    const int tid  = threadIdx.x;
    const int lane = tid & 63;
    const int wid  = tid >> 6;
    const int wr = wid >> 2, wc = wid & 3;      // 2M x 4N waves; 128x64 out each
    const int l31  = lane & 31;
    const int hi8e = (lane >> 5) * 8;           // k-half select (32x32x16 A/B layout)
    const int sx   = (lane & 7) << 3;           // read-side XOR: (row&7)<<3 elements

    int bid = blockIdx.x;
    int wg  = (bid & 7) * 32 + (bid >> 3);      // bijective XCD swizzle (256 wgs)
    int by = wg >> 3, bx = wg & 7;
    const int bm = by * 256, bn = bx * 256;

    // staging source coords: linear LDS dest L -> swizzled global (r,c); involution
    int r_[2], c_[2];
#pragma unroll
    for (int i = 0; i < 2; ++i) {
        int L = i * 4096 + tid * 8;                 // element index within half-tile
        int S = L ^ (((L >> 6) & 7) << 3);          // XOR col bits 3-5 with row bits 0-2
        r_[i] = S >> 6; c_[i] = S & 63;
    }

    auto stA = [&](int buf, int h, int kt) {
#pragma unroll
        for (int i = 0; i < 2; ++i) {
            const short* src = A + (size_t)(bm + h * 128 + r_[i]) * KDIM + kt * 64 + c_[i];
            __builtin_amdgcn_global_load_lds(
                (const __attribute__((address_space(1))) void*)src,
                (__attribute__((address_space(3))) void*)&lds[buf * 16384 + h * 8192 + i * 4096 + tid * 8],
                16, 0, 0);
        }
    };
    auto stB = [&](int buf, int h, int kt) {
#pragma unroll
        for (int i = 0; i < 2; ++i) {
            const short* src = B + (size_t)(bn + h * 128 + r_[i]) * KDIM + kt * 64 + c_[i];
            __builtin_amdgcn_global_load_lds(
                (const __attribute__((address_space(1))) void*)src,
                (__attribute__((address_space(3))) void*)&lds[32768 + buf * 16384 + h * 8192 + i * 4096 + tid * 8],
                16, 0, 0);
        }
    };

    f32x16 acc[4][2] = {};
    bf16x8 bfr[2][4];
    bf16x8 afr[4];

    // ---- prologue: A(0),B(0) -> buf0; B(1) -> buf1; wait all but B(1) ----
    stA(0, 0, 0); stA(0, 1, 0);
    stB(0, 0, 0); stB(0, 1, 0);
    stB(1, 0, 1); stB(1, 1, 1);
    asm volatile("s_waitcnt vmcnt(4)" ::: "memory");
    SBAR();

    // 32 K-tiles, 2 per iteration. Stage schedule (region freed one barrier earlier):
    // P1,P2: A(t1)->Abuf1   P3,P4: B(t2)->Bbuf0   P5,P6: A(t2)->Abuf0   P7,P8: B(t3)->Bbuf1
    // vmcnt(4) at P4/P8 leaves only the 2 newest half-tiles in flight.
    for (int i = 0; i < 16; ++i) {
        int t1 = 2 * i + 1, t2 = (2 * i + 2) & 31, t3 = (2 * i + 3) & 31;
        // P1
        LDB32(0); LDA32(0, 0); stA(1, 0, t1);
        SBAR(); MM32(0); SBAR();
        // P2
        LDA32(0, 1); stA(1, 1, t1);
        SBAR(); MM32(1); SBAR();
        // P3
        LDA32(0, 2); stB(0, 0, t2);
        SBAR(); MM32(2); SBAR();
        // P4
        LDA32(0, 3); stB(0, 1, t2);
        SBAR(); MM32(3);
        asm volatile("s_waitcnt vmcnt(4)" ::: "memory");
        SBAR();
        // P5
        LDB32(1); LDA32(1, 0); stA(0, 0, t2);
        SBAR(); MM32(0); SBAR();
        // P6
        LDA32(1, 1); stA(0, 1, t2);
        SBAR(); MM32(1); SBAR();
        // P7
        LDA32(1, 2); stB(1, 0, t3);
        SBAR(); MM32(2); SBAR();
        // P8
        LDA32(1, 3); stB(1, 1, t3);
        SBAR(); MM32(3);
        asm volatile("s_waitcnt vmcnt(4)" ::: "memory");
        SBAR();
    }
    asm volatile("s_waitcnt vmcnt(0)" ::: "memory");

    // epilogue: 32x32 C/D layout col=lane&31, row=(reg&3)+8*(reg>>2)+4*(lane>>5)
    // [m74/m101-verified]
    int c0 = bn + wc * 64 + l31;
#pragma unroll
    for (int mt = 0; mt < 4; ++mt) {
        int r0 = bm + wr * 128 + mt * 32 + (lane >> 5) * 4;
#pragma unroll
        for (int nt = 0; nt < 2; ++nt)
#pragma unroll
            for (int reg = 0; reg < 16; ++reg)
                C[(size_t)(r0 + (reg & 3) + 8 * (reg >> 2)) * NDIM + c0 + nt * 32] =
                    acc[mt][nt][reg];
    }
}

extern "C" void kernel_launch(void* const* d_in, const int* in_sizes, int n_in,
                              void* d_out, int out_size, void* d_ws, size_t ws_size,
                              hipStream_t stream) {
    const float* x       = (const float*)d_in[0];   // [8192,8,256]
    const float* alpha   = (const float*)d_in[1];   // [1]
    const float* u_param = (const float*)d_in[2];   // [8,8]
    const float* T       = (const float*)d_in[3];   // [8,8,256,256]
    float* out = (float*)d_out;                     // [8192,8,256]

    short* Abf = (short*)d_ws;                                     // 32 MiB
    short* Bp  = (short*)((char*)d_ws + (size_t)BATCH * KDIM * 2); // 8 MiB

    hipLaunchKernelGGL(pack_a, dim3((BATCH * KDIM / 8) / 256), dim3(256), 0, stream, x, Abf);
    hipLaunchKernelGGL(pack_b, dim3(512), dim3(256), 0, stream, T, u_param, alpha, Bp);
    hipLaunchKernelGGL(gemm, dim3((BATCH / 256) * (NDIM / 256)), dim3(512), 0, stream,
                       Abf, Bp, out);
}